// Round 10
// baseline (79.288 us; speedup 1.0000x reference)
//
#include <hip/hip_runtime.h>

// channel_attention: the attention branch is the identity (softmax over m
// sums to 1 in einsum 'bdct,bdcm->bdct'). Output = LN_c(pW @ x + pb) per
// (b,d,t) column.
//
// R9 = R8 (67.4us) with stores escalated from builtin-nt to inline-asm
// "sc0 sc1 nt" (system-scope non-temporal) -- full L2/L3 write-around.
// Theory: builtin nt only sets the L2 hint; the 197MB out stream still
// allocates in memory-side Infinity Cache, evicting half of x each replay
// (FETCH=96MB ~ x/2). If out bypasses L3, x (196.6MB < 256MB) goes
// resident and HBM approaches a pure write stream (~7 TB/s fill rate).

#define CC      64
#define TT      3000
#define TILE_T  128
#define NTB     24            // ceil(TT / TILE_T)
#define NWG     (256 * NTB)   // 6144 blocks, % 8 == 0 -> bijective swizzle
#define CPX     (NWG / 8)     // 768

typedef __attribute__((ext_vector_type(8)))  short short8;
typedef __attribute__((ext_vector_type(16))) float f32x16;
typedef __attribute__((ext_vector_type(4)))  float f32x4;

static __device__ __forceinline__ unsigned f2bf(float f) {
    // round-to-nearest-even f32 -> bf16 (inputs finite)
    unsigned u = __builtin_bit_cast(unsigned, f);
    return (u + 0x7FFFu + ((u >> 16) & 1u)) >> 16;
}

static __device__ __forceinline__ void store_bypass(float* p, f32x4 v) {
    // system-scope non-temporal: write around L2 and Infinity Cache.
    asm volatile("global_store_dwordx4 %0, %1, off sc0 sc1 nt"
                 :: "v"(p), "v"(v) : "memory");
}

// ws layout: Wf = 4096 shorts (8 KB); Pf = 192 floats at +8192 B.
// Wf[((ct*4+kc)*64 + lane)*8 + e] = bf16(pW[co*CC + c]),
//   co = ct*32 + (lane&31), c = kc*16 + (lane>>5)*8 + e.
// Pf[a*64 + (ct*2+half)*16 + r] = {pb,pg,pbeta}[ct*32 + half*4 + (r&3) + 8*(r>>2)]
__global__ void pack_params(const float* __restrict__ pW,
                            const float* __restrict__ pb,
                            const float* __restrict__ pg,
                            const float* __restrict__ pbeta,
                            short* __restrict__ Wf, float* __restrict__ Pf)
{
    int i = blockIdx.x * 256 + threadIdx.x;
    if (i < 4096) {
        int e = i & 7, l = (i >> 3) & 63, f = i >> 9;
        int ct = f >> 2, kc = f & 3;
        int co = ct * 32 + (l & 31);
        int c  = kc * 16 + (l >> 5) * 8 + e;
        Wf[i] = (short)f2bf(pW[co * CC + c]);
    } else if (i < 4096 + 192) {
        int j = i - 4096;
        int a = j >> 6, q = j & 63;
        int r = q & 15, half = (q >> 4) & 1, ct = q >> 5;
        int co = ct * 32 + half * 4 + (r & 3) + 8 * (r >> 2);
        const float* src = (a == 0) ? pb : (a == 1) ? pg : pbeta;
        Pf[j] = src[co];
    }
}

__global__ __launch_bounds__(256, 4) void fused_mfma_ln(
    const float* __restrict__ x,    // [BD, CC, TT]
    const short* __restrict__ Wf,
    const float* __restrict__ Pf,
    float* __restrict__ out)        // [BD, CC, TT]
{
    __shared__ float xy[CC * TILE_T];   // 32 KB, [c][t] f32; reused for y

    const int bid = blockIdx.x;
    const int swz = (bid & 7) * CPX + (bid >> 3);   // XCD-chunked, bijective
    const int bd  = swz / NTB;
    const int tb  = swz - bd * NTB;
    const int t0b = tb * TILE_T;

    const int tid  = threadIdx.x;
    const int lane = tid & 63;
    const int wid  = tid >> 6;
    const int col  = lane & 31;
    const int half = lane >> 5;

    const size_t xbase = (size_t)bd * (CC * TT);

    // W fragments: 8 x 16B loads, issued first to overlap with staging.
    short8 aW[2][4];
#pragma unroll
    for (int ct = 0; ct < 2; ++ct)
#pragma unroll
        for (int kc = 0; kc < 4; ++kc)
            aW[ct][kc] = ((const short8*)Wf)[(ct * 4 + kc) * 64 + lane];

    // ---- Phase 1: stage x[64][128] f32 -> LDS via float4 (512B/row segs).
    // round r: lanes 0-31 cover row c (full 128-t span), lanes 32-63 row c+1.
    int tq = t0b + col * 4;
    if (tq > TT - 4) tq = TT - 4;       // tail clamp (dup data, never stored)
    float4 tmp[8];
#pragma unroll
    for (int r = 0; r < 8; ++r) {
        const int c = r * 8 + wid * 2 + half;
        tmp[r] = *(const float4*)(x + xbase + (size_t)c * TT + tq);
    }
#pragma unroll
    for (int r = 0; r < 8; ++r) {
        const int c = r * 8 + wid * 2 + half;
        *(float4*)&xy[c * TILE_T + col * 4] = tmp[r];   // b128, conflict-free
    }
    __syncthreads();

    // ---- Phase 2: B-frags from LDS (b32 reads, lanes stride 4B: free),
    // pack to bf16. Same (kc, half, e)->c rule as aW -> permutation cancels.
    const int tcol = wid * 32 + col;    // this wave's 32 columns
    short8 bx[4];
#pragma unroll
    for (int kc = 0; kc < 4; ++kc) {
        union { unsigned u[4]; short8 s; } cvt;
#pragma unroll
        for (int p = 0; p < 4; ++p) {
            const float a = xy[(kc * 16 + half * 8 + 2 * p)     * TILE_T + tcol];
            const float b = xy[(kc * 16 + half * 8 + 2 * p + 1) * TILE_T + tcol];
            cvt.u[p] = f2bf(a) | (f2bf(b) << 16);
        }
        bx[kc] = cvt.s;
    }

    f32x16 acc[2];
#pragma unroll
    for (int r = 0; r < 16; ++r) { acc[0][r] = 0.0f; acc[1][r] = 0.0f; }
#pragma unroll
    for (int kc = 0; kc < 4; ++kc) {
        acc[0] = __builtin_amdgcn_mfma_f32_32x32x16_bf16(aW[0][kc], bx[kc], acc[0], 0, 0, 0);
        acc[1] = __builtin_amdgcn_mfma_f32_32x32x16_bf16(aW[1][kc], bx[kc], acc[1], 0, 0, 0);
    }

    // ---- Phase 3: bias + LN stats (C/D layout: col=lane&31,
    // row = ct*32 + half*4 + (r&3) + 8*(r>>2)); shfl_xor(32) joins halves.
    float s = 0.0f, s2 = 0.0f;
#pragma unroll
    for (int ct = 0; ct < 2; ++ct) {
        const float4* pbv = (const float4*)(Pf + (ct * 2 + half) * 16);
#pragma unroll
        for (int q = 0; q < 4; ++q) {
            const float4 b4 = pbv[q];
            acc[ct][q * 4 + 0] += b4.x;
            acc[ct][q * 4 + 1] += b4.y;
            acc[ct][q * 4 + 2] += b4.z;
            acc[ct][q * 4 + 3] += b4.w;
        }
#pragma unroll
        for (int r = 0; r < 16; ++r) {
            const float v = acc[ct][r];
            s += v;
            s2 = fmaf(v, v, s2);
        }
    }
    s  += __shfl_xor(s, 32);
    s2 += __shfl_xor(s2, 32);
    const float mu   = s * (1.0f / CC);
    const float rstd = rsqrtf(s2 * (1.0f / CC) - mu * mu + 1e-5f);

    // ---- Phase 4: write final outputs back into the SAME LDS buffer.
    // Wave w touches only its own 32 columns -> safe aliasing, one barrier.
#pragma unroll
    for (int ct = 0; ct < 2; ++ct) {
        const float4* pgv = (const float4*)(Pf + 64  + (ct * 2 + half) * 16);
        const float4* pev = (const float4*)(Pf + 128 + (ct * 2 + half) * 16);
#pragma unroll
        for (int q = 0; q < 4; ++q) {
            const float4 g4 = pgv[q];
            const float4 e4 = pev[q];
            const float gg[4] = {g4.x, g4.y, g4.z, g4.w};
            const float ee[4] = {e4.x, e4.y, e4.z, e4.w};
#pragma unroll
            for (int j = 0; j < 4; ++j) {
                const int r  = q * 4 + j;
                const int co = ct * 32 + half * 4 + (r & 3) + 8 * (r >> 2);
                xy[co * TILE_T + tcol] = (acc[ct][r] - mu) * rstd * gg[j] + ee[j];
            }
        }
    }
    __syncthreads();

    // ---- Phase 5: vectorized L2/L3-bypass stores (sc0 sc1 nt). Mirror of
    // phase 1 (512B/row segments).
    const bool stok = (t0b + col * 4) < TT;   // quad-aligned (TT % 4 == 0)
#pragma unroll
    for (int r = 0; r < 8; ++r) {
        const int c = r * 8 + wid * 2 + half;
        const f32x4 v = *(const f32x4*)&xy[c * TILE_T + col * 4];
        if (stok)
            store_bypass(out + xbase + (size_t)c * TT + t0b + col * 4, v);
    }
    // Compiler can't count inline-asm stores; drain before endpgm.
    asm volatile("s_waitcnt vmcnt(0)" ::: "memory");
}

extern "C" void kernel_launch(void* const* d_in, const int* in_sizes, int n_in,
                              void* d_out, int out_size, void* d_ws, size_t ws_size,
                              hipStream_t stream) {
    // setup_inputs order: x, qW, qb, qg, qbeta, kW, kb, kg, kbeta, pW, pb, pg, pbeta
    const float* x     = (const float*)d_in[0];
    const float* pW    = (const float*)d_in[9];
    const float* pb    = (const float*)d_in[10];
    const float* pg    = (const float*)d_in[11];
    const float* pbeta = (const float*)d_in[12];
    float* out = (float*)d_out;

    short* Wf = (short*)d_ws;                          // 8 KB
    float* Pf = (float*)((char*)d_ws + 8192);          // 768 B

    pack_params<<<17, 256, 0, stream>>>(pW, pb, pg, pbeta, Wf, Pf);

    dim3 grid(NWG);         // 6144 blocks
    dim3 block(256);
    fused_mfma_ln<<<grid, block, 0, stream>>>(x, Wf, Pf, out);
}

// Round 11
// 73.719 us; speedup vs baseline: 1.0755x; 1.0755x over previous
//
#include <hip/hip_runtime.h>

// channel_attention: the attention branch is the identity (softmax over m
// sums to 1 in einsum 'bdct,bdcm->bdct'). Output = LN_c(pW @ x + pb) per
// (b,d,t) column.
//
// R10 = R8 structure (best, 67.4us: f32 loads -> LDS -> MFMA -> LN -> nt
// stores) with LDS staged as bf16 (16KB vs 32KB) so 6 blocks/CU fit
// (launch_bounds(256,6)) instead of 4 -> +50% in-flight memory ops.
// x->bf16 costs nothing (MFMA input was bf16 already); y->bf16 writeback
// adds <=0.008 output rounding (absmax 0.031 -> ~0.05, thr 0.0988).
// R9's sc0sc1nt bypass falsified (FETCH unchanged, time +12us) -> builtin
// nontemporal stores restored.

#define CC      64
#define TT      3000
#define TILE_T  128
#define NTB     24            // ceil(TT / TILE_T)
#define NWG     (256 * NTB)   // 6144 blocks, % 8 == 0 -> bijective swizzle
#define CPX     (NWG / 8)     // 768

typedef __attribute__((ext_vector_type(8)))  short short8;
typedef __attribute__((ext_vector_type(16))) float f32x16;
typedef __attribute__((ext_vector_type(4)))  float f32x4;

static __device__ __forceinline__ unsigned f2bf(float f) {
    // round-to-nearest-even f32 -> bf16 (inputs finite)
    unsigned u = __builtin_bit_cast(unsigned, f);
    return (u + 0x7FFFu + ((u >> 16) & 1u)) >> 16;
}

// ws layout: Wf = 4096 shorts (8 KB); Pf = 192 floats at +8192 B.
// Wf[((ct*4+kc)*64 + lane)*8 + e] = bf16(pW[co*CC + c]),
//   co = ct*32 + (lane&31), c = kc*16 + (lane>>5)*8 + e.
// Pf[a*64 + (ct*2+half)*16 + r] = {pb,pg,pbeta}[ct*32 + half*4 + (r&3) + 8*(r>>2)]
__global__ void pack_params(const float* __restrict__ pW,
                            const float* __restrict__ pb,
                            const float* __restrict__ pg,
                            const float* __restrict__ pbeta,
                            short* __restrict__ Wf, float* __restrict__ Pf)
{
    int i = blockIdx.x * 256 + threadIdx.x;
    if (i < 4096) {
        int e = i & 7, l = (i >> 3) & 63, f = i >> 9;
        int ct = f >> 2, kc = f & 3;
        int co = ct * 32 + (l & 31);
        int c  = kc * 16 + (l >> 5) * 8 + e;
        Wf[i] = (short)f2bf(pW[co * CC + c]);
    } else if (i < 4096 + 192) {
        int j = i - 4096;
        int a = j >> 6, q = j & 63;
        int r = q & 15, half = (q >> 4) & 1, ct = q >> 5;
        int co = ct * 32 + half * 4 + (r & 3) + 8 * (r >> 2);
        const float* src = (a == 0) ? pb : (a == 1) ? pg : pbeta;
        Pf[j] = src[co];
    }
}

__global__ __launch_bounds__(256, 6) void fused_mfma_ln(
    const float* __restrict__ x,    // [BD, CC, TT]
    const short* __restrict__ Wf,
    const float* __restrict__ Pf,
    float* __restrict__ out)        // [BD, CC, TT]
{
    __shared__ unsigned short xs[CC * TILE_T];   // 16 KB: [c][t] bf16; x then y

    const int bid = blockIdx.x;
    const int swz = (bid & 7) * CPX + (bid >> 3);   // XCD-chunked, bijective
    const int bd  = swz / NTB;
    const int tb  = swz - bd * NTB;
    const int t0b = tb * TILE_T;

    const int tid  = threadIdx.x;
    const int lane = tid & 63;
    const int wid  = tid >> 6;
    const int col  = lane & 31;
    const int half = lane >> 5;

    const size_t xbase = (size_t)bd * (CC * TT);

    // W fragments: 8 x 16B loads, issued first to overlap with staging.
    short8 aW[2][4];
#pragma unroll
    for (int ct = 0; ct < 2; ++ct)
#pragma unroll
        for (int kc = 0; kc < 4; ++kc)
            aW[ct][kc] = ((const short8*)Wf)[(ct * 4 + kc) * 64 + lane];

    // ---- Phase 1: stage x -> bf16 LDS via float4 loads (512B/row segs).
    // round r: lanes 0-31 cover row c (full 128-t span), lanes 32-63 row c+1.
    int tq = t0b + col * 4;
    if (tq > TT - 4) tq = TT - 4;       // tail clamp (dup data, never stored)
    float4 tmp[8];
#pragma unroll
    for (int r = 0; r < 8; ++r) {
        const int c = r * 8 + wid * 2 + half;
        tmp[r] = *(const float4*)(x + xbase + (size_t)c * TT + tq);
    }
#pragma unroll
    for (int r = 0; r < 8; ++r) {
        const int c = r * 8 + wid * 2 + half;
        uint2 p;
        p.x = f2bf(tmp[r].x) | (f2bf(tmp[r].y) << 16);
        p.y = f2bf(tmp[r].z) | (f2bf(tmp[r].w) << 16);
        *(uint2*)&xs[c * TILE_T + col * 4] = p;   // ds_write_b64, conflict-free
    }
    __syncthreads();

    // ---- Phase 2: B-frags from bf16 LDS (u16 reads, pair-pack to dwords).
    // Same (kc, half, e)->c rule as aW -> within-K permutation cancels.
    const int tcol = wid * 32 + col;    // this wave's 32 columns
    short8 bx[4];
#pragma unroll
    for (int kc = 0; kc < 4; ++kc) {
        union { unsigned u[4]; short8 s; } cvt;
#pragma unroll
        for (int e = 0; e < 4; ++e) {
            const int c0 = kc * 16 + half * 8 + 2 * e;
            cvt.u[e] = (unsigned)xs[c0 * TILE_T + tcol]
                     | ((unsigned)xs[(c0 + 1) * TILE_T + tcol] << 16);
        }
        bx[kc] = cvt.s;
    }

    f32x16 acc[2];
#pragma unroll
    for (int r = 0; r < 16; ++r) { acc[0][r] = 0.0f; acc[1][r] = 0.0f; }
#pragma unroll
    for (int kc = 0; kc < 4; ++kc) {
        acc[0] = __builtin_amdgcn_mfma_f32_32x32x16_bf16(aW[0][kc], bx[kc], acc[0], 0, 0, 0);
        acc[1] = __builtin_amdgcn_mfma_f32_32x32x16_bf16(aW[1][kc], bx[kc], acc[1], 0, 0, 0);
    }

    // ---- Phase 3: bias + LN stats (C/D layout: col=lane&31,
    // row = ct*32 + half*4 + (r&3) + 8*(r>>2)); shfl_xor(32) joins halves.
    float s = 0.0f, s2 = 0.0f;
#pragma unroll
    for (int ct = 0; ct < 2; ++ct) {
        const float4* pbv = (const float4*)(Pf + (ct * 2 + half) * 16);
#pragma unroll
        for (int q = 0; q < 4; ++q) {
            const float4 b4 = pbv[q];
            acc[ct][q * 4 + 0] += b4.x;
            acc[ct][q * 4 + 1] += b4.y;
            acc[ct][q * 4 + 2] += b4.z;
            acc[ct][q * 4 + 3] += b4.w;
        }
#pragma unroll
        for (int r = 0; r < 16; ++r) {
            const float v = acc[ct][r];
            s += v;
            s2 = fmaf(v, v, s2);
        }
    }
    s  += __shfl_xor(s, 32);
    s2 += __shfl_xor(s2, 32);
    const float mu   = s * (1.0f / CC);
    const float rstd = rsqrtf(s2 * (1.0f / CC) - mu * mu + 1e-5f);

    // ---- Phase 4: y writeback (bf16) into the same buffer, own columns
    // only -> safe aliasing, one barrier.
#pragma unroll
    for (int ct = 0; ct < 2; ++ct) {
        const float4* pgv = (const float4*)(Pf + 64  + (ct * 2 + half) * 16);
        const float4* pev = (const float4*)(Pf + 128 + (ct * 2 + half) * 16);
#pragma unroll
        for (int q = 0; q < 4; ++q) {
            const float4 g4 = pgv[q];
            const float4 e4 = pev[q];
            const float gg[4] = {g4.x, g4.y, g4.z, g4.w};
            const float ee[4] = {e4.x, e4.y, e4.z, e4.w};
#pragma unroll
            for (int j = 0; j < 4; ++j) {
                const int r  = q * 4 + j;
                const int co = ct * 32 + half * 4 + (r & 3) + 8 * (r >> 2);
                const float val = (acc[ct][r] - mu) * rstd * gg[j] + ee[j];
                xs[co * TILE_T + tcol] = (unsigned short)f2bf(val);
            }
        }
    }
    __syncthreads();

    // ---- Phase 5: mirror of phase 1. uint2 (4 bf16) -> f32 expand ->
    // nontemporal float4 store; 512B/row, 2 rows per instruction.
    const bool stok = (t0b + col * 4) < TT;   // quad-aligned (TT % 4 == 0)
#pragma unroll
    for (int r = 0; r < 8; ++r) {
        const int c = r * 8 + wid * 2 + half;
        const uint2 v = *(const uint2*)&xs[c * TILE_T + col * 4];
        if (stok) {
            f32x4 o;
            o[0] = __builtin_bit_cast(float, v.x << 16);
            o[1] = __builtin_bit_cast(float, v.x & 0xFFFF0000u);
            o[2] = __builtin_bit_cast(float, v.y << 16);
            o[3] = __builtin_bit_cast(float, v.y & 0xFFFF0000u);
            __builtin_nontemporal_store(
                o, (f32x4*)(out + xbase + (size_t)c * TT + t0b + col * 4));
        }
    }
}

extern "C" void kernel_launch(void* const* d_in, const int* in_sizes, int n_in,
                              void* d_out, int out_size, void* d_ws, size_t ws_size,
                              hipStream_t stream) {
    // setup_inputs order: x, qW, qb, qg, qbeta, kW, kb, kg, kbeta, pW, pb, pg, pbeta
    const float* x     = (const float*)d_in[0];
    const float* pW    = (const float*)d_in[9];
    const float* pb    = (const float*)d_in[10];
    const float* pg    = (const float*)d_in[11];
    const float* pbeta = (const float*)d_in[12];
    float* out = (float*)d_out;

    short* Wf = (short*)d_ws;                          // 8 KB
    float* Pf = (float*)((char*)d_ws + 8192);          // 768 B

    pack_params<<<17, 256, 0, stream>>>(pW, pb, pg, pbeta, Wf, Pf);

    dim3 grid(NWG);         // 6144 blocks
    dim3 block(256);
    fused_mfma_ln<<<grid, block, 0, stream>>>(x, Wf, Pf, out);
}

// Round 12
// 68.107 us; speedup vs baseline: 1.1642x; 1.0824x over previous
//
#include <hip/hip_runtime.h>

// channel_attention: the attention branch is the identity (softmax over m
// sums to 1 in einsum 'bdct,bdcm->bdct'). Output = LN_c(pW @ x + pb) per
// (b,d,t) column.
//
// R11 = R8 (best, 67.4us) + global_load_lds DMA staging (phase 1).
// Config space probed: occupancy 6 blocks/CU (R10) inflates WRITE 192->225MB
// (partial-line NT evictions; rows are 32B-phase misaligned since
// TT*4=12000 % 64 = 32) and regresses; 1KB segments (R7) likewise; sc0sc1nt
// L3 bypass (R9) has no effect on FETCH. R8's point -- 4 blocks/CU, 512B
// segments, f32 LDS, builtin-NT stores -- is the measured optimum.
// The DMA staging removes the load->VGPR->ds_write round-trip: LDS dest is
// wave-uniform base (row r*8+wid*2) + lane*16B (lanes 32-63 continue into
// row+1, matching their global source row), global source per-lane.

#define CC      64
#define TT      3000
#define TILE_T  128
#define NTB     24            // ceil(TT / TILE_T)
#define NWG     (256 * NTB)   // 6144 blocks, % 8 == 0 -> bijective swizzle
#define CPX     (NWG / 8)     // 768

typedef __attribute__((ext_vector_type(8)))  short short8;
typedef __attribute__((ext_vector_type(16))) float f32x16;
typedef __attribute__((ext_vector_type(4)))  float f32x4;

static __device__ __forceinline__ unsigned f2bf(float f) {
    // round-to-nearest-even f32 -> bf16 (inputs finite)
    unsigned u = __builtin_bit_cast(unsigned, f);
    return (u + 0x7FFFu + ((u >> 16) & 1u)) >> 16;
}

static __device__ __forceinline__ void load_lds16(const float* g, float* lds) {
    // 16B-per-lane DMA: LDS dest = wave-uniform base + lane*16.
    __builtin_amdgcn_global_load_lds(
        (const __attribute__((address_space(1))) unsigned*)g,
        (__attribute__((address_space(3))) unsigned*)lds, 16, 0, 0);
}

// ws layout: Wf = 4096 shorts (8 KB); Pf = 192 floats at +8192 B.
// Wf[((ct*4+kc)*64 + lane)*8 + e] = bf16(pW[co*CC + c]),
//   co = ct*32 + (lane&31), c = kc*16 + (lane>>5)*8 + e.
// Pf[a*64 + (ct*2+half)*16 + r] = {pb,pg,pbeta}[ct*32 + half*4 + (r&3) + 8*(r>>2)]
__global__ void pack_params(const float* __restrict__ pW,
                            const float* __restrict__ pb,
                            const float* __restrict__ pg,
                            const float* __restrict__ pbeta,
                            short* __restrict__ Wf, float* __restrict__ Pf)
{
    int i = blockIdx.x * 256 + threadIdx.x;
    if (i < 4096) {
        int e = i & 7, l = (i >> 3) & 63, f = i >> 9;
        int ct = f >> 2, kc = f & 3;
        int co = ct * 32 + (l & 31);
        int c  = kc * 16 + (l >> 5) * 8 + e;
        Wf[i] = (short)f2bf(pW[co * CC + c]);
    } else if (i < 4096 + 192) {
        int j = i - 4096;
        int a = j >> 6, q = j & 63;
        int r = q & 15, half = (q >> 4) & 1, ct = q >> 5;
        int co = ct * 32 + half * 4 + (r & 3) + 8 * (r >> 2);
        const float* src = (a == 0) ? pb : (a == 1) ? pg : pbeta;
        Pf[j] = src[co];
    }
}

__global__ __launch_bounds__(256, 4) void fused_mfma_ln(
    const float* __restrict__ x,    // [BD, CC, TT]
    const short* __restrict__ Wf,
    const float* __restrict__ Pf,
    float* __restrict__ out)        // [BD, CC, TT]
{
    __shared__ float xy[CC * TILE_T];   // 32 KB, [c][t] f32; reused for y

    const int bid = blockIdx.x;
    const int swz = (bid & 7) * CPX + (bid >> 3);   // XCD-chunked, bijective
    const int bd  = swz / NTB;
    const int tb  = swz - bd * NTB;
    const int t0b = tb * TILE_T;

    const int tid  = threadIdx.x;
    const int lane = tid & 63;
    const int wid  = tid >> 6;
    const int col  = lane & 31;
    const int half = lane >> 5;

    const size_t xbase = (size_t)bd * (CC * TT);

    // W fragments: 8 x 16B loads, issued first to overlap with staging.
    short8 aW[2][4];
#pragma unroll
    for (int ct = 0; ct < 2; ++ct)
#pragma unroll
        for (int kc = 0; kc < 4; ++kc)
            aW[ct][kc] = ((const short8*)Wf)[(ct * 4 + kc) * 64 + lane];

    // ---- Phase 1: DMA-stage x[64][128] f32 -> LDS (512B/row segments).
    // Instr r: lanes 0-31 cover row c0=r*8+wid*2 (cols col*4..col*4+3),
    // lanes 32-63 land at ldsbase+lane*16 = row c0+1 -- matching their
    // global source row c0+1. Per-lane global addr, uniform LDS base.
    int tq = t0b + col * 4;
    if (tq > TT - 4) tq = TT - 4;       // tail clamp (dup data, never stored)
#pragma unroll
    for (int r = 0; r < 8; ++r) {
        const int c  = r * 8 + wid * 2 + half;   // this lane's source row
        const int c0 = r * 8 + wid * 2;          // wave-uniform dest row
        load_lds16(x + xbase + (size_t)c * TT + tq, &xy[c0 * TILE_T]);
    }
    __syncthreads();

    // ---- Phase 2: B-frags from LDS (b32 reads, lanes stride 4B: free),
    // pack to bf16. Same (kc, half, e)->c rule as aW -> permutation cancels.
    const int tcol = wid * 32 + col;    // this wave's 32 columns
    short8 bx[4];
#pragma unroll
    for (int kc = 0; kc < 4; ++kc) {
        union { unsigned u[4]; short8 s; } cvt;
#pragma unroll
        for (int p = 0; p < 4; ++p) {
            const float a = xy[(kc * 16 + half * 8 + 2 * p)     * TILE_T + tcol];
            const float b = xy[(kc * 16 + half * 8 + 2 * p + 1) * TILE_T + tcol];
            cvt.u[p] = f2bf(a) | (f2bf(b) << 16);
        }
        bx[kc] = cvt.s;
    }

    f32x16 acc[2];
#pragma unroll
    for (int r = 0; r < 16; ++r) { acc[0][r] = 0.0f; acc[1][r] = 0.0f; }
#pragma unroll
    for (int kc = 0; kc < 4; ++kc) {
        acc[0] = __builtin_amdgcn_mfma_f32_32x32x16_bf16(aW[0][kc], bx[kc], acc[0], 0, 0, 0);
        acc[1] = __builtin_amdgcn_mfma_f32_32x32x16_bf16(aW[1][kc], bx[kc], acc[1], 0, 0, 0);
    }

    // ---- Phase 3: bias + LN stats (C/D layout: col=lane&31,
    // row = ct*32 + half*4 + (r&3) + 8*(r>>2)); shfl_xor(32) joins halves.
    float s = 0.0f, s2 = 0.0f;
#pragma unroll
    for (int ct = 0; ct < 2; ++ct) {
        const float4* pbv = (const float4*)(Pf + (ct * 2 + half) * 16);
#pragma unroll
        for (int q = 0; q < 4; ++q) {
            const float4 b4 = pbv[q];
            acc[ct][q * 4 + 0] += b4.x;
            acc[ct][q * 4 + 1] += b4.y;
            acc[ct][q * 4 + 2] += b4.z;
            acc[ct][q * 4 + 3] += b4.w;
        }
#pragma unroll
        for (int r = 0; r < 16; ++r) {
            const float v = acc[ct][r];
            s += v;
            s2 = fmaf(v, v, s2);
        }
    }
    s  += __shfl_xor(s, 32);
    s2 += __shfl_xor(s2, 32);
    const float mu   = s * (1.0f / CC);
    const float rstd = rsqrtf(s2 * (1.0f / CC) - mu * mu + 1e-5f);

    // ---- Phase 4: write final outputs back into the SAME LDS buffer.
    // Wave w touches only its own 32 columns -> safe aliasing, one barrier.
#pragma unroll
    for (int ct = 0; ct < 2; ++ct) {
        const float4* pgv = (const float4*)(Pf + 64  + (ct * 2 + half) * 16);
        const float4* pev = (const float4*)(Pf + 128 + (ct * 2 + half) * 16);
#pragma unroll
        for (int q = 0; q < 4; ++q) {
            const float4 g4 = pgv[q];
            const float4 e4 = pev[q];
            const float gg[4] = {g4.x, g4.y, g4.z, g4.w};
            const float ee[4] = {e4.x, e4.y, e4.z, e4.w};
#pragma unroll
            for (int j = 0; j < 4; ++j) {
                const int r  = q * 4 + j;
                const int co = ct * 32 + half * 4 + (r & 3) + 8 * (r >> 2);
                xy[co * TILE_T + tcol] = (acc[ct][r] - mu) * rstd * gg[j] + ee[j];
            }
        }
    }
    __syncthreads();

    // ---- Phase 5: vectorized NON-TEMPORAL stores (mirror of phase 1;
    // 512B/row segments, 2 rows per instruction).
    const bool stok = (t0b + col * 4) < TT;   // quad-aligned (TT % 4 == 0)
#pragma unroll
    for (int r = 0; r < 8; ++r) {
        const int c = r * 8 + wid * 2 + half;
        const f32x4 v = *(const f32x4*)&xy[c * TILE_T + col * 4];
        if (stok)
            __builtin_nontemporal_store(
                v, (f32x4*)(out + xbase + (size_t)c * TT + t0b + col * 4));
    }
}

extern "C" void kernel_launch(void* const* d_in, const int* in_sizes, int n_in,
                              void* d_out, int out_size, void* d_ws, size_t ws_size,
                              hipStream_t stream) {
    // setup_inputs order: x, qW, qb, qg, qbeta, kW, kb, kg, kbeta, pW, pb, pg, pbeta
    const float* x     = (const float*)d_in[0];
    const float* pW    = (const float*)d_in[9];
    const float* pb    = (const float*)d_in[10];
    const float* pg    = (const float*)d_in[11];
    const float* pbeta = (const float*)d_in[12];
    float* out = (float*)d_out;

    short* Wf = (short*)d_ws;                          // 8 KB
    float* Pf = (float*)((char*)d_ws + 8192);          // 768 B

    pack_params<<<17, 256, 0, stream>>>(pW, pb, pg, pbeta, Wf, Pf);

    dim3 grid(NWG);         // 6144 blocks
    dim3 block(256);
    fused_mfma_ln<<<grid, block, 0, stream>>>(x, Wf, Pf, out);
}